// Round 9
// baseline (463.216 us; speedup 1.0000x reference)
//
#include <hip/hip_runtime.h>
#include <math.h>

// HashGrid: 8 LODs, hashed trilinear interp, 1 feature/entry, summed over LODs.
// LODS  = [17, 27, 44, 71, 116, 191, 313, res7(host-computed, 512 or 513)]
// SIZES = [4913, 19683, 85184, 357911, 2^19, 2^19, 2^19, 2^19]
// codebook layout: [8][524288][1] float32.
//
// R9: deep gather pipeline via global_load_lds (async gather -> LDS landing
// slots, no dst VGPR, vmcnt-counted). R8's asm gather-to-VGPR crashed: LLVM
// may move/spill in-flight asm output regs. Here the register allocator has
// nothing to break: per-lane global address, wave-uniform LDS dest, counted
// s_waitcnt vmcnt(N) ledger, 32 outstanding gathers per wave.

static constexpr unsigned CB_STRIDE = 524288u;
// packed bf16 ws element offsets (all even -> dword-align trick works)
static constexpr unsigned WO0 = 0;        // 4913
static constexpr unsigned WO1 = 4928;     // 19683
static constexpr unsigned WO2 = 24640;    // 85184
static constexpr unsigned WO3 = 109824;   // 357911
static constexpr unsigned WO4 = 467744;   // 524288
static constexpr unsigned WO5 = 992032;   // 524288
static constexpr unsigned WO6 = 1516320;  // 524288
static constexpr unsigned WO7 = 2040608;  // 524288 -> end 2564896
static constexpr size_t WS_NEED_BYTES = 2564896u * 2u;  // 5.13 MB

__device__ __forceinline__ unsigned short f32_to_bf16_rne(float f) {
    unsigned u = __float_as_uint(f);
    u = (u + 0x7FFFu + ((u >> 16) & 1u)) >> 16;
    return (unsigned short)u;
}

#define TO_GLB(p) ((const __attribute__((address_space(1))) void*)(p))
#define TO_LDS(p) ((__attribute__((address_space(3))) void*)(p))

// async gather of the aligned dword containing bf16 entry (wo+v) into
// lds slot (wave-uniform base; HW writes base + lane*4). vmcnt-counted.
__device__ __forceinline__ void gld(const unsigned short* ws, unsigned elem,
                                    unsigned* lds_dst)
{
    const char* g = (const char*)ws + ((elem * 2u) & ~3u);
    __builtin_amdgcn_global_load_lds(TO_GLB(g), TO_LDS(lds_dst), 4, 0, 0);
}

#define VMWAIT(N) do { \
    asm volatile("s_waitcnt vmcnt(" #N ")" ::: "memory"); \
    __builtin_amdgcn_sched_barrier(0); \
} while (0)

struct LodState { unsigned selm; float fx, fy, fz; };

template <unsigned SIZE, bool POW2>
__device__ __forceinline__ LodState issue_lod(float p01x, float p01y, float p01z,
                                              int res, unsigned wo,
                                              const unsigned short* __restrict__ ws,
                                              unsigned* slot /* [8][64] */)
{
    const float rm1 = (float)(res - 1);
    float xx = p01x * rm1, yy = p01y * rm1, zz = p01z * rm1;
    const float cmax = (float)(res - 2);
    float fx = fminf(fmaxf(floorf(xx), 0.0f), cmax);
    float fy = fminf(fmaxf(floorf(yy), 0.0f), cmax);
    float fz = fminf(fmaxf(floorf(zz), 0.0f), cmax);
    LodState st;
    st.fx = xx - fx; st.fy = yy - fy; st.fz = zz - fz;
    const unsigned ix = (unsigned)(int)fx;
    const unsigned iy = (unsigned)(int)fy;
    const unsigned iz = (unsigned)(int)fz;

    const unsigned hx0 = ix;                  // PRIME0 = 1
    const unsigned hx1 = ix + 1u;
    const unsigned hy0 = iy * 2654435761u;
    const unsigned hy1 = hy0 + 2654435761u;
    const unsigned hz0 = iz * 805459861u;
    const unsigned hz1 = hz0 + 805459861u;

    unsigned v0 = hx0 ^ hy0 ^ hz0;
    unsigned v1 = hx0 ^ hy0 ^ hz1;
    unsigned v2 = hx0 ^ hy1 ^ hz0;
    unsigned v3 = hx0 ^ hy1 ^ hz1;
    unsigned v4 = hx1 ^ hy0 ^ hz0;
    unsigned v5 = hx1 ^ hy0 ^ hz1;
    unsigned v6 = hx1 ^ hy1 ^ hz0;
    unsigned v7 = hx1 ^ hy1 ^ hz1;

    if (POW2) {
        const unsigned m = SIZE - 1u;
        v0 &= m; v1 &= m; v2 &= m; v3 &= m; v4 &= m; v5 &= m; v6 &= m; v7 &= m;
    } else {
        v0 %= SIZE; v1 %= SIZE; v2 %= SIZE; v3 %= SIZE;
        v4 %= SIZE; v5 %= SIZE; v6 %= SIZE; v7 %= SIZE;
    }

    st.selm = ((wo + v0) & 1u)        | (((wo + v1) & 1u) << 1)
            | (((wo + v2) & 1u) << 2) | (((wo + v3) & 1u) << 3)
            | (((wo + v4) & 1u) << 4) | (((wo + v5) & 1u) << 5)
            | (((wo + v6) & 1u) << 6) | (((wo + v7) & 1u) << 7);

    gld(ws, wo + v0, slot + 0 * 64);
    gld(ws, wo + v1, slot + 1 * 64);
    gld(ws, wo + v2, slot + 2 * 64);
    gld(ws, wo + v3, slot + 3 * 64);
    gld(ws, wo + v4, slot + 4 * 64);
    gld(ws, wo + v5, slot + 5 * 64);
    gld(ws, wo + v6, slot + 6 * 64);
    gld(ws, wo + v7, slot + 7 * 64);
    return st;
}

__device__ __forceinline__ float pick(unsigned d, unsigned sel) {
    return __uint_as_float(sel ? (d & 0xffff0000u) : (d << 16));
}

__device__ __forceinline__ float consume_slot(const unsigned* slot, int lane,
                                              const LodState& st)
{
    const unsigned d0 = slot[0 * 64 + lane];
    const unsigned d1 = slot[1 * 64 + lane];
    const unsigned d2 = slot[2 * 64 + lane];
    const unsigned d3 = slot[3 * 64 + lane];
    const unsigned d4 = slot[4 * 64 + lane];
    const unsigned d5 = slot[5 * 64 + lane];
    const unsigned d6 = slot[6 * 64 + lane];
    const unsigned d7 = slot[7 * 64 + lane];

    const float t000 = pick(d0, (st.selm >> 0) & 1u);
    const float t001 = pick(d1, (st.selm >> 1) & 1u);
    const float t010 = pick(d2, (st.selm >> 2) & 1u);
    const float t011 = pick(d3, (st.selm >> 3) & 1u);
    const float t100 = pick(d4, (st.selm >> 4) & 1u);
    const float t101 = pick(d5, (st.selm >> 5) & 1u);
    const float t110 = pick(d6, (st.selm >> 6) & 1u);
    const float t111 = pick(d7, (st.selm >> 7) & 1u);

    const float wx1 = st.fx, wx0 = 1.0f - st.fx;
    const float wy1 = st.fy, wy0 = 1.0f - st.fy;
    const float wz1 = st.fz, wz0 = 1.0f - st.fz;
    const float w00 = wy0 * wz0, w01 = wy0 * wz1;
    const float w10 = wy1 * wz0, w11 = wy1 * wz1;
    const float sx0 = t000 * w00 + t001 * w01 + t010 * w10 + t011 * w11;
    const float sx1 = t100 * w00 + t101 * w01 + t110 * w10 + t111 * w11;
    return wx0 * sx0 + wx1 * sx1;
}

// prep: convert all 8 LOD table prefixes to packed bf16 in ws
__global__ __launch_bounds__(1024)
void HashGrid_convert_kernel(const float* __restrict__ codebook,
                             unsigned short* __restrict__ ws)
{
    const int lod = blockIdx.y;  // 0..7
    const int sizes[8] = {4913, 19683, 85184, 357911, 524288, 524288, 524288, 524288};
    const unsigned offs[8] = {WO0, WO1, WO2, WO3, WO4, WO5, WO6, WO7};
    const int idx = blockIdx.x * 1024 + threadIdx.x;
    if (idx < sizes[lod])
        ws[offs[lod] + idx] = f32_to_bf16_rne(codebook[(unsigned)lod * CB_STRIDE + idx]);
}

__global__ __launch_bounds__(256, 4)
void HashGrid_88278757802387_kernel(const float* __restrict__ pts,
                                    const unsigned short* __restrict__ ws,
                                    float* __restrict__ out,
                                    int n, int res7)
{
    __shared__ unsigned lbuf[4][4][8][64];  // wave x ring-slot x corner x lane; 32 KB
    const int w    = threadIdx.x >> 6;
    const int lane = threadIdx.x & 63;
    unsigned* s0 = &lbuf[w][0][0][0];
    unsigned* s1 = &lbuf[w][1][0][0];
    unsigned* s2 = &lbuf[w][2][0][0];
    unsigned* s3 = &lbuf[w][3][0][0];

    const int i = blockIdx.x * 256 + threadIdx.x;
    if (i >= n) return;

    const float p01x = __builtin_nontemporal_load(pts + 3 * i + 0) * 0.5f + 0.5f;
    const float p01y = __builtin_nontemporal_load(pts + 3 * i + 1) * 0.5f + 0.5f;
    const float p01z = __builtin_nontemporal_load(pts + 3 * i + 2) * 0.5f + 0.5f;

    // fill: 32 outstanding
    LodState st7 = issue_lod<524288u, true >(p01x, p01y, p01z, res7, WO7, ws, s0);
    LodState st6 = issue_lod<524288u, true >(p01x, p01y, p01z, 313,  WO6, ws, s1);
    LodState st5 = issue_lod<524288u, true >(p01x, p01y, p01z, 191,  WO5, ws, s2);
    LodState st4 = issue_lod<524288u, true >(p01x, p01y, p01z, 116,  WO4, ws, s3);

    // steady state: retire oldest 8, consume, reissue 8
    VMWAIT(24);
    float acc = consume_slot(s0, lane, st7);
    LodState st3 = issue_lod<357911u, false>(p01x, p01y, p01z, 71, WO3, ws, s0);

    VMWAIT(24);
    acc += consume_slot(s1, lane, st6);
    LodState st2 = issue_lod<85184u,  false>(p01x, p01y, p01z, 44, WO2, ws, s1);

    VMWAIT(24);
    acc += consume_slot(s2, lane, st5);
    LodState st1 = issue_lod<19683u,  false>(p01x, p01y, p01z, 27, WO1, ws, s2);

    VMWAIT(24);
    acc += consume_slot(s3, lane, st4);
    LodState st0 = issue_lod<4913u,   false>(p01x, p01y, p01z, 17, WO0, ws, s3);

    // drain
    VMWAIT(24);
    acc += consume_slot(s0, lane, st3);
    VMWAIT(16);
    acc += consume_slot(s1, lane, st2);
    VMWAIT(8);
    acc += consume_slot(s2, lane, st1);
    VMWAIT(0);
    acc += consume_slot(s3, lane, st0);

    __builtin_nontemporal_store(acc, out + i);
}

// fallback (no ws): per-LOD f32 path straight from codebook
__global__ __launch_bounds__(256, 4)
void HashGrid_fallback_kernel(const float* __restrict__ pts,
                              const float* __restrict__ codebook,
                              float* __restrict__ out,
                              int n, int res7)
{
    const int i = blockIdx.x * 256 + threadIdx.x;
    if (i >= n) return;
    const float p01x = pts[3 * i + 0] * 0.5f + 0.5f;
    const float p01y = pts[3 * i + 1] * 0.5f + 0.5f;
    const float p01z = pts[3 * i + 2] * 0.5f + 0.5f;
    float acc = 0.0f;
    const int      reslist[8]  = {17, 27, 44, 71, 116, 191, 313, res7};
    const unsigned sizelist[8] = {4913u, 19683u, 85184u, 357911u, 524288u, 524288u, 524288u, 524288u};
    for (int l = 0; l < 8; ++l) {
        const int res = reslist[l];
        const unsigned size = sizelist[l];
        const float rm1 = (float)(res - 1);
        float xx = p01x * rm1, yy = p01y * rm1, zz = p01z * rm1;
        float fx = fminf(fmaxf(floorf(xx), 0.0f), (float)(res - 2));
        float fy = fminf(fmaxf(floorf(yy), 0.0f), (float)(res - 2));
        float fz = fminf(fmaxf(floorf(zz), 0.0f), (float)(res - 2));
        const float frx = xx - fx, fry = yy - fy, frz = zz - fz;
        const unsigned ix = (unsigned)(int)fx, iy = (unsigned)(int)fy, iz = (unsigned)(int)fz;
        const unsigned hy0 = iy * 2654435761u, hy1 = hy0 + 2654435761u;
        const unsigned hz0 = iz * 805459861u,  hz1 = hz0 + 805459861u;
        const unsigned o0 = (ix ^ hy0 ^ hz0) % size,      o1 = (ix ^ hy0 ^ hz1) % size;
        const unsigned o2 = (ix ^ hy1 ^ hz0) % size,      o3 = (ix ^ hy1 ^ hz1) % size;
        const unsigned o4 = ((ix+1u) ^ hy0 ^ hz0) % size, o5 = ((ix+1u) ^ hy0 ^ hz1) % size;
        const unsigned o6 = ((ix+1u) ^ hy1 ^ hz0) % size, o7 = ((ix+1u) ^ hy1 ^ hz1) % size;
        const float* tab = codebook + (unsigned)l * CB_STRIDE;
        const float wx1 = frx, wx0 = 1.0f - frx;
        const float wy1 = fry, wy0 = 1.0f - fry;
        const float wz1 = frz, wz0 = 1.0f - frz;
        const float w00 = wy0*wz0, w01 = wy0*wz1, w10 = wy1*wz0, w11 = wy1*wz1;
        acc += wx0 * (tab[o0]*w00 + tab[o1]*w01 + tab[o2]*w10 + tab[o3]*w11)
             + wx1 * (tab[o4]*w00 + tab[o5]*w01 + tab[o6]*w10 + tab[o7]*w11);
    }
    out[i] = acc;
}

extern "C" void kernel_launch(void* const* d_in, const int* in_sizes, int n_in,
                              void* d_out, int out_size, void* d_ws, size_t ws_size,
                              hipStream_t stream)
{
    const float* pts      = (const float*)d_in[0];
    const float* codebook = (const float*)d_in[1];
    float* out            = (float*)d_out;
    const int n = in_sizes[0] / 3;

    // numpy-matching LOD7 resolution (16*b^7 sits ~1e-12 from 512.0)
    const double b = exp((log(512.0) - log(16.0)) / 7.0);
    const int res7 = (int)(1.0 + floor(16.0 * pow(b, 7.0)));

    const bool use_ws = (d_ws != nullptr) && (ws_size >= WS_NEED_BYTES);
    const int blocks = (n + 255) / 256;

    if (use_ws) {
        unsigned short* ws = (unsigned short*)d_ws;
        hipLaunchKernelGGL(HashGrid_convert_kernel, dim3(512, 8), dim3(1024),
                           0, stream, codebook, ws);
        hipLaunchKernelGGL(HashGrid_88278757802387_kernel, dim3(blocks), dim3(256),
                           0, stream, pts, ws, out, n, res7);
    } else {
        hipLaunchKernelGGL(HashGrid_fallback_kernel, dim3(blocks), dim3(256),
                           0, stream, pts, codebook, out, n, res7);
    }
}

// Round 10
// 349.819 us; speedup vs baseline: 1.3242x; 1.3242x over previous
//
#include <hip/hip_runtime.h>
#include <math.h>

// HashGrid: 8 LODs, hashed trilinear interp, 1 feature/entry, summed over LODs.
// LODS  = [17, 27, 44, 71, 116, 191, 313, res7(host-computed, 512 or 513)]
// SIZES = [4913, 19683, 85184, 357911, 2^19, 2^19, 2^19, 2^19]
// codebook layout: [8][524288][1] float32.
//
// R10: established wall = per-CU gather-request throughput ~0.5 lane-req/cyc
// (R9: 3x in-flight depth -> no change). Attack request COUNT:
//  - LOD0/1 from LDS (16 requests off the TCP path)  [R5 structure, 406us]
//  - pow2 LODs 4..7: x-pair dword merge. PRIME0=1 -> i_x1 = i_x0 ^ 1 for
//    even ix; ws offsets even -> both x-corners in ONE aligned dword for any
//    v0 parity. 4 dword loads + 4 exec-masked u16 loads (odd-ix lanes only)
//    = 6 avg req/LOD vs 8. Total 48 -> 40 req/pt (-17%).
//  - scalars only, (1024,4): R5 proved no scratch in this shape (R6's spill
//    was the (1024,8) VGPR-32 clamp).

static constexpr unsigned CB_STRIDE = 524288u;
static constexpr int S0 = 4913;    // 17^3
static constexpr int S1 = 19683;   // 27^3
// ws (bf16) element offsets for LOD2..7 (all EVEN -> dword pairing valid)
static constexpr unsigned WO2 = 0;        // 85184
static constexpr unsigned WO3 = 85184;    // 357911
static constexpr unsigned WO4 = 443104;   // 524288
static constexpr unsigned WO5 = 967392;
static constexpr unsigned WO6 = 1491680;
static constexpr unsigned WO7 = 2015968;
static constexpr size_t WS_NEED_BYTES = 2540256u * 2u;  // 5.08 MB

__device__ __forceinline__ unsigned short f32_to_bf16_rne(float f) {
    unsigned u = __float_as_uint(f);
    u = (u + 0x7FFFu + ((u >> 16) & 1u)) >> 16;
    return (unsigned short)u;
}
__device__ __forceinline__ float bf16_to_f32(unsigned short s) {
    return __uint_as_float(((unsigned)s) << 16);
}

struct I8 { unsigned a0, a1, a2, a3, a4, a5, a6, a7; };
struct R8 { unsigned short v0, v1, v2, v3, v4, v5, v6, v7; };
struct W3 { float x, y, z; };

template <unsigned SIZE, bool POW2>
__device__ __forceinline__ I8 idx8(float p01x, float p01y, float p01z, int res, W3& fr)
{
    const float rm1 = (float)(res - 1);
    float xx = p01x * rm1, yy = p01y * rm1, zz = p01z * rm1;
    const float cmax = (float)(res - 2);
    float fx = fminf(fmaxf(floorf(xx), 0.0f), cmax);
    float fy = fminf(fmaxf(floorf(yy), 0.0f), cmax);
    float fz = fminf(fmaxf(floorf(zz), 0.0f), cmax);
    fr.x = xx - fx; fr.y = yy - fy; fr.z = zz - fz;
    const unsigned ix = (unsigned)(int)fx;
    const unsigned iy = (unsigned)(int)fy;
    const unsigned iz = (unsigned)(int)fz;

    const unsigned hx0 = ix;                  // PRIME0 = 1
    const unsigned hx1 = ix + 1u;
    const unsigned hy0 = iy * 2654435761u;
    const unsigned hy1 = hy0 + 2654435761u;
    const unsigned hz0 = iz * 805459861u;
    const unsigned hz1 = hz0 + 805459861u;

    unsigned v0 = hx0 ^ hy0 ^ hz0;
    unsigned v1 = hx0 ^ hy0 ^ hz1;
    unsigned v2 = hx0 ^ hy1 ^ hz0;
    unsigned v3 = hx0 ^ hy1 ^ hz1;
    unsigned v4 = hx1 ^ hy0 ^ hz0;
    unsigned v5 = hx1 ^ hy0 ^ hz1;
    unsigned v6 = hx1 ^ hy1 ^ hz0;
    unsigned v7 = hx1 ^ hy1 ^ hz1;

    if (POW2) {
        const unsigned m = SIZE - 1u;
        v0 &= m; v1 &= m; v2 &= m; v3 &= m; v4 &= m; v5 &= m; v6 &= m; v7 &= m;
    } else {
        v0 %= SIZE; v1 %= SIZE; v2 %= SIZE; v3 %= SIZE;
        v4 %= SIZE; v5 %= SIZE; v6 %= SIZE; v7 %= SIZE;
    }
    I8 o; o.a0 = v0; o.a1 = v1; o.a2 = v2; o.a3 = v3;
          o.a4 = v4; o.a5 = v5; o.a6 = v6; o.a7 = v7;
    return o;
}

__device__ __forceinline__ R8 gather8(const unsigned short* __restrict__ t, I8 o)
{
    R8 r;
    r.v0 = t[o.a0]; r.v1 = t[o.a1]; r.v2 = t[o.a2]; r.v3 = t[o.a3];
    r.v4 = t[o.a4]; r.v5 = t[o.a5]; r.v6 = t[o.a6]; r.v7 = t[o.a7];
    return r;
}

__device__ __forceinline__ float acc8(R8 r, W3 f)
{
    const float wx1 = f.x, wx0 = 1.0f - f.x;
    const float wy1 = f.y, wy0 = 1.0f - f.y;
    const float wz1 = f.z, wz0 = 1.0f - f.z;
    const float w00 = wy0 * wz0, w01 = wy0 * wz1;
    const float w10 = wy1 * wz0, w11 = wy1 * wz1;
    const float sx0 = bf16_to_f32(r.v0) * w00 + bf16_to_f32(r.v1) * w01
                    + bf16_to_f32(r.v2) * w10 + bf16_to_f32(r.v3) * w11;
    const float sx1 = bf16_to_f32(r.v4) * w00 + bf16_to_f32(r.v5) * w01
                    + bf16_to_f32(r.v6) * w10 + bf16_to_f32(r.v7) * w11;
    return wx0 * sx0 + wx1 * sx1;
}

// pow2 LOD (size 2^19) with x-pair dword merge. wo must be EVEN.
// For ix even: v_x1 = v_x0 ^ 1 -> both corners in the aligned dword at
// element (wo+v)&~1. For ix odd: 4 extra exec-masked u16 loads.
__device__ __forceinline__ float lod_pow2_merged(float p01x, float p01y, float p01z,
                                                 int res,
                                                 const unsigned short* __restrict__ t)
{
    const float rm1 = (float)(res - 1);
    float xx = p01x * rm1, yy = p01y * rm1, zz = p01z * rm1;
    const float cmax = (float)(res - 2);
    float fx = fminf(fmaxf(floorf(xx), 0.0f), cmax);
    float fy = fminf(fmaxf(floorf(yy), 0.0f), cmax);
    float fz = fminf(fmaxf(floorf(zz), 0.0f), cmax);
    const float frx = xx - fx, fry = yy - fy, frz = zz - fz;
    const unsigned ix = (unsigned)(int)fx;
    const unsigned iy = (unsigned)(int)fy;
    const unsigned iz = (unsigned)(int)fz;

    const unsigned hy0 = iy * 2654435761u, hy1 = hy0 + 2654435761u;
    const unsigned hz0 = iz * 805459861u,  hz1 = hz0 + 805459861u;
    const unsigned m = 524287u;

    const unsigned e00 = (ix ^ hy0 ^ hz0) & m;
    const unsigned e01 = (ix ^ hy0 ^ hz1) & m;
    const unsigned e10 = (ix ^ hy1 ^ hz0) & m;
    const unsigned e11 = (ix ^ hy1 ^ hz1) & m;

    // aligned dwords; each covers elements {e&~1, e|1} = {e, e^1}
    const unsigned* t32 = reinterpret_cast<const unsigned*>(t);
    const unsigned p00 = t32[e00 >> 1];
    const unsigned p01 = t32[e01 >> 1];
    const unsigned p10 = t32[e10 >> 1];
    const unsigned p11 = t32[e11 >> 1];

    const bool oddx = (ix & 1u) != 0u;
    unsigned short q00 = 0, q01 = 0, q10 = 0, q11 = 0;
    if (oddx) {
        const unsigned hx1 = ix + 1u;
        q00 = t[(hx1 ^ hy0 ^ hz0) & m];
        q01 = t[(hx1 ^ hy0 ^ hz1) & m];
        q10 = t[(hx1 ^ hy1 ^ hz0) & m];
        q11 = t[(hx1 ^ hy1 ^ hz1) & m];
    }

    // unpack: x0 corner = half 'sel' of pair; x1 = other half (even ix) or q.
    const unsigned s00 = e00 & 1u, s01 = e01 & 1u, s10 = e10 & 1u, s11 = e11 & 1u;
    const float a00 = bf16_to_f32((unsigned short)(s00 ? (p00 >> 16) : (p00 & 0xffffu)));
    const float a01 = bf16_to_f32((unsigned short)(s01 ? (p01 >> 16) : (p01 & 0xffffu)));
    const float a10 = bf16_to_f32((unsigned short)(s10 ? (p10 >> 16) : (p10 & 0xffffu)));
    const float a11 = bf16_to_f32((unsigned short)(s11 ? (p11 >> 16) : (p11 & 0xffffu)));
    const float b00 = bf16_to_f32(oddx ? q00 : (unsigned short)(s00 ? (p00 & 0xffffu) : (p00 >> 16)));
    const float b01 = bf16_to_f32(oddx ? q01 : (unsigned short)(s01 ? (p01 & 0xffffu) : (p01 >> 16)));
    const float b10 = bf16_to_f32(oddx ? q10 : (unsigned short)(s10 ? (p10 & 0xffffu) : (p10 >> 16)));
    const float b11 = bf16_to_f32(oddx ? q11 : (unsigned short)(s11 ? (p11 & 0xffffu) : (p11 >> 16)));

    const float wx1 = frx, wx0 = 1.0f - frx;
    const float wy1 = fry, wy0 = 1.0f - fry;
    const float wz1 = frz, wz0 = 1.0f - frz;
    const float w00 = wy0 * wz0, w01 = wy0 * wz1;
    const float w10 = wy1 * wz0, w11 = wy1 * wz1;
    const float sx0 = a00 * w00 + a01 * w01 + a10 * w10 + a11 * w11;
    const float sx1 = b00 * w00 + b01 * w01 + b10 * w10 + b11 * w11;
    return wx0 * sx0 + wx1 * sx1;
}

// prep: convert LOD2..7 table prefixes to bf16 in ws
__global__ __launch_bounds__(1024)
void HashGrid_convert_kernel(const float* __restrict__ codebook,
                             unsigned short* __restrict__ ws)
{
    const int lod = blockIdx.y;  // 0..5 -> LOD2..7
    const int sizes[6] = {85184, 357911, 524288, 524288, 524288, 524288};
    const unsigned offs[6] = {WO2, WO3, WO4, WO5, WO6, WO7};
    const int idx = blockIdx.x * 1024 + threadIdx.x;
    if (idx < sizes[lod])
        ws[offs[lod] + idx] = f32_to_bf16_rne(codebook[(unsigned)(lod + 2) * CB_STRIDE + idx]);
}

__global__ __launch_bounds__(1024, 4)
void HashGrid_88278757802387_kernel(const float* __restrict__ pts,
                                    const float* __restrict__ codebook,
                                    const unsigned short* __restrict__ ws,
                                    float* __restrict__ out,
                                    int n, int res7)
{
    __shared__ unsigned short sm[S0 + S1];  // 49.2 KB
    for (int j = threadIdx.x; j < S0 + S1; j += 1024)
        sm[j] = f32_to_bf16_rne(j < S0 ? codebook[j] : codebook[CB_STRIDE + (j - S0)]);
    __syncthreads();

    const int i = blockIdx.x * 1024 + threadIdx.x;
    if (i >= n) return;

    const float p01x = pts[3 * i + 0] * 0.5f + 0.5f;
    const float p01y = pts[3 * i + 1] * 0.5f + 0.5f;
    const float p01z = pts[3 * i + 2] * 0.5f + 0.5f;

    // mod tables: issue 16 u16 gathers early (consumed last, FIFO-friendly)
    W3 fA, fB, fL0, fL1;
    I8 oA = idx8<85184u,  false>(p01x, p01y, p01z, 44, fA);
    I8 oB = idx8<357911u, false>(p01x, p01y, p01z, 71, fB);
    R8 rA = gather8(ws + WO2, oA);
    R8 rB = gather8(ws + WO3, oB);

    // pow2 tables: merged x-pair loads (avg 6 requests each vs 8)
    float acc = lod_pow2_merged(p01x, p01y, p01z, 116,  ws + WO4);
    acc      += lod_pow2_merged(p01x, p01y, p01z, 191,  ws + WO5);
    acc      += lod_pow2_merged(p01x, p01y, p01z, 313,  ws + WO6);
    acc      += lod_pow2_merged(p01x, p01y, p01z, res7, ws + WO7);

    // LDS LODs (off the TCP path)
    I8 oL0 = idx8<4913u,  false>(p01x, p01y, p01z, 17, fL0);
    I8 oL1 = idx8<19683u, false>(p01x, p01y, p01z, 27, fL1);
    R8 rL0 = gather8(sm, oL0);
    R8 rL1 = gather8(sm + S0, oL1);
    acc += acc8(rL0, fL0) + acc8(rL1, fL1);

    // consume the mod-table batches
    acc += acc8(rA, fA) + acc8(rB, fB);

    out[i] = acc;
}

// fallback (no ws): per-LOD f32 path straight from codebook
__global__ __launch_bounds__(1024, 4)
void HashGrid_fallback_kernel(const float* __restrict__ pts,
                              const float* __restrict__ codebook,
                              float* __restrict__ out,
                              int n, int res7)
{
    const int i = blockIdx.x * 1024 + threadIdx.x;
    if (i >= n) return;
    const float p01x = pts[3 * i + 0] * 0.5f + 0.5f;
    const float p01y = pts[3 * i + 1] * 0.5f + 0.5f;
    const float p01z = pts[3 * i + 2] * 0.5f + 0.5f;
    float acc = 0.0f;
    const int      reslist[8]  = {17, 27, 44, 71, 116, 191, 313, res7};
    const unsigned sizelist[8] = {4913u, 19683u, 85184u, 357911u, 524288u, 524288u, 524288u, 524288u};
    for (int l = 0; l < 8; ++l) {
        const int res = reslist[l];
        const unsigned size = sizelist[l];
        const float rm1 = (float)(res - 1);
        float xx = p01x * rm1, yy = p01y * rm1, zz = p01z * rm1;
        float fx = fminf(fmaxf(floorf(xx), 0.0f), (float)(res - 2));
        float fy = fminf(fmaxf(floorf(yy), 0.0f), (float)(res - 2));
        float fz = fminf(fmaxf(floorf(zz), 0.0f), (float)(res - 2));
        const float frx = xx - fx, fry = yy - fy, frz = zz - fz;
        const unsigned ix = (unsigned)(int)fx, iy = (unsigned)(int)fy, iz = (unsigned)(int)fz;
        const unsigned hy0 = iy * 2654435761u, hy1 = hy0 + 2654435761u;
        const unsigned hz0 = iz * 805459861u,  hz1 = hz0 + 805459861u;
        const unsigned o0 = (ix ^ hy0 ^ hz0) % size,      o1 = (ix ^ hy0 ^ hz1) % size;
        const unsigned o2 = (ix ^ hy1 ^ hz0) % size,      o3 = (ix ^ hy1 ^ hz1) % size;
        const unsigned o4 = ((ix+1u) ^ hy0 ^ hz0) % size, o5 = ((ix+1u) ^ hy0 ^ hz1) % size;
        const unsigned o6 = ((ix+1u) ^ hy1 ^ hz0) % size, o7 = ((ix+1u) ^ hy1 ^ hz1) % size;
        const float* tab = codebook + (unsigned)l * CB_STRIDE;
        const float wx1 = frx, wx0 = 1.0f - frx;
        const float wy1 = fry, wy0 = 1.0f - fry;
        const float wz1 = frz, wz0 = 1.0f - frz;
        const float w00 = wy0*wz0, w01 = wy0*wz1, w10 = wy1*wz0, w11 = wy1*wz1;
        acc += wx0 * (tab[o0]*w00 + tab[o1]*w01 + tab[o2]*w10 + tab[o3]*w11)
             + wx1 * (tab[o4]*w00 + tab[o5]*w01 + tab[o6]*w10 + tab[o7]*w11);
    }
    out[i] = acc;
}

extern "C" void kernel_launch(void* const* d_in, const int* in_sizes, int n_in,
                              void* d_out, int out_size, void* d_ws, size_t ws_size,
                              hipStream_t stream)
{
    const float* pts      = (const float*)d_in[0];
    const float* codebook = (const float*)d_in[1];
    float* out            = (float*)d_out;
    const int n = in_sizes[0] / 3;

    // numpy-matching LOD7 resolution (16*b^7 sits ~1e-12 from 512.0)
    const double b = exp((log(512.0) - log(16.0)) / 7.0);
    const int res7 = (int)(1.0 + floor(16.0 * pow(b, 7.0)));

    const bool use_ws = (d_ws != nullptr) && (ws_size >= WS_NEED_BYTES);
    const int blocks = (n + 1023) / 1024;

    if (use_ws) {
        unsigned short* ws = (unsigned short*)d_ws;
        hipLaunchKernelGGL(HashGrid_convert_kernel, dim3(512, 6), dim3(1024),
                           0, stream, codebook, ws);
        hipLaunchKernelGGL(HashGrid_88278757802387_kernel, dim3(blocks), dim3(1024),
                           0, stream, pts, codebook, ws, out, n, res7);
    } else {
        hipLaunchKernelGGL(HashGrid_fallback_kernel, dim3(blocks), dim3(1024),
                           0, stream, pts, codebook, out, n, res7);
    }
}